// Round 1
// baseline (1479.922 us; speedup 1.0000x reference)
//
#include <hip/hip_runtime.h>
#include <stdint.h>
#include <stddef.h>

#define DH 2048
#define DI 64
#define DO_ 64
#define T_ 512
#define BB 128

typedef __attribute__((ext_vector_type(8))) short bf16x8;
typedef __attribute__((ext_vector_type(4))) float f32x4;

__device__ __forceinline__ unsigned short f2bf(float x) {
    union { float f; unsigned u; } v; v.f = x;
    unsigned r = v.u + 0x7fffu + ((v.u >> 16) & 1u);   // RTNE
    return (unsigned short)(r >> 16);
}
__device__ __forceinline__ float bf2f(unsigned short h) {
    union { unsigned u; float f; } v; v.u = ((unsigned)h) << 16;
    return v.f;
}
__device__ __forceinline__ float sigm(float x) {
    return __builtin_amdgcn_rcpf(1.0f + __expf(-x));
}

// K-permutation within each 32-wide K block for mfma_f32_16x16x32_bf16 operands.
// Assumed HW layout (two stacked K=16 halves, per tr_b16-verified mapping):
//   elem e0..3 -> k = 4*G + e        (G = lane>>4)
//   elem e4..7 -> k = 16 + 4*G + (e-4)
// Storage column c is arranged so lane G's 16B load at byte 16*G is exactly its frag.
// FALLBACK if validation fails: contiguous-8 layout == identity perm (k_of_c(c)=c, c_of_k(k)=k).
__device__ __forceinline__ int c_of_k(int k32) {
    return 8 * ((k32 >> 2) & 3) + (k32 & 3) + 4 * (k32 >> 4);
}
__device__ __forceinline__ int k_of_c(int c32) {
    int G = c32 >> 3, e = c32 & 7;
    return 4 * G + (e & 3) + 16 * (e >> 2);
}

// ---------------- prologue: sigmoid(r0), pack win (hi/lo split) & wout to bf16, k-permuted ----
__global__ __launch_bounds__(256) void k_prep(
    const float* __restrict__ r0, const float* __restrict__ win,
    const float* __restrict__ wout, float* __restrict__ sig_r0,
    unsigned short* __restrict__ win_hi, unsigned short* __restrict__ win_lo,
    unsigned short* __restrict__ wout_p)
{
    int idx = blockIdx.x * 256 + threadIdx.x;
    if (idx < DH * BB) sig_r0[idx] = sigm(r0[idx]);
    if (idx < DH * DI) {                       // win: [2048][64], perm within each 32-k block
        int h = idx >> 6, c = idx & 63;
        int k = (c & 32) + k_of_c(c & 31);
        float x = win[h * DI + k];
        unsigned short hi = f2bf(x);
        win_hi[idx] = hi;
        win_lo[idx] = f2bf(x - bf2f(hi));
    }
    if (idx < DO_ * DH) {                      // wout: [64][2048]
        int o = idx >> 11, c = idx & 2047;
        int k = (c & ~31) + k_of_c(c & 31);
        wout_p[idx] = f2bf(wout[o * DH + k]);
    }
}

// ---------------- prologue: base = (1-alpha)*r0 + alpha * (|_w| @ sig_r0) -------------------
// 256 blocks x 8 h-rows; thread owns 1 h x 4 b. S (1 MB) stays L2-resident.
__global__ __launch_bounds__(256) void k_base(
    const float* __restrict__ w_, const float* __restrict__ r0,
    const float* __restrict__ taus, const float* __restrict__ sig_r0,
    float* __restrict__ base)
{
    const int tid = threadIdx.x;
    const int h = blockIdx.x * 8 + (tid >> 5);
    const int bg = (tid & 31) * 4;
    const float* wr = w_ + (size_t)h * DH;
    float a0 = 0.f, a1 = 0.f, a2 = 0.f, a3 = 0.f;
    for (int k = 0; k < DH; k += 4) {
        float4 wv = *(const float4*)(wr + k);
        #pragma unroll
        for (int kk = 0; kk < 4; ++kk) {
            float w = fabsf((&wv.x)[kk]);
            float4 s4 = *(const float4*)(sig_r0 + (size_t)(k + kk) * BB + bg);
            a0 += w * s4.x; a1 += w * s4.y; a2 += w * s4.z; a3 += w * s4.w;
        }
    }
    const float alpha = 1.0f / taus[h];        // DT = 1.0
    const float om = 1.0f - alpha;
    float* bp = base + (size_t)h * BB + bg;
    const float* rp = r0 + (size_t)h * BB + bg;
    bp[0] = om * rp[0] + alpha * a0;
    bp[1] = om * rp[1] + alpha * a1;
    bp[2] = om * rp[2] + alpha * a2;
    bp[3] = om * rp[3] + alpha * a3;
}

// ---------------- main: per-t fused  xs = base + win@u + noise ; out = wout@sigmoid(xs) -----
__global__ __launch_bounds__(512, 4) void k_main(
    const float* __restrict__ u, const float* __restrict__ noise,
    const float* __restrict__ base, const unsigned short* __restrict__ win_hi,
    const unsigned short* __restrict__ win_lo, const unsigned short* __restrict__ wout_p,
    const float* __restrict__ bias, float* __restrict__ out, float* __restrict__ xs)
{
    __shared__ __align__(16) unsigned short u_hi[DI * BB];   // [b=128][c(d)=64] bf16, 16 KB
    __shared__ __align__(16) unsigned short u_lo[DI * BB];   // 16 KB
    __shared__ __align__(16) unsigned short s_lds[BB * BB];  // [b=128][c(h)=128] bf16, 32 KB

    const int t = blockIdx.x;
    const int tid = threadIdx.x;
    const int lane = tid & 63;
    const int wid = tid >> 6;
    const int g = lane >> 4;
    const int c15 = lane & 15;

    // ---- stage u[t] (DI x BB) -> LDS transposed [b][c(d)], bf16 hi/lo, XOR-swizzled ----
    {
        const int b = tid >> 2;                 // 0..127
        const int dg = tid & 3;                 // 16-d group
        const float* up = u + (size_t)t * DI * BB + (size_t)(dg * 16) * BB + b;
        const int swz = (b & 7) << 4;
        const int rowb = b * 128;               // 64 bf16 per row = 128 B
        const int cb = 32 * (dg >> 1) + 4 * (dg & 1);
        #pragma unroll
        for (int G4 = 0; G4 < 4; ++G4) {
            unsigned long long phi = 0ull, plo = 0ull;
            #pragma unroll
            for (int e = 0; e < 4; ++e) {
                float x = up[(G4 * 4 + e) * BB];
                unsigned short hi = f2bf(x);
                unsigned short lo = f2bf(x - bf2f(hi));
                phi |= (unsigned long long)hi << (16 * e);
                plo |= (unsigned long long)lo << (16 * e);
            }
            const int off = (rowb + 2 * (cb + 8 * G4)) ^ swz;
            *(unsigned long long*)((char*)u_hi + off) = phi;
            *(unsigned long long*)((char*)u_lo + off) = plo;
        }
    }
    __syncthreads();

    const int wm = wid >> 1;    // GEMM1 row block (32 rows each)
    const int wn = wid & 1;     // GEMM1 col block (64 cols each)
    f32x4 acc2[4] = {};         // GEMM2 accumulators (o = mf*16 rows, wave's 16 b cols)

    for (int ch = 0; ch < 16; ++ch) {
        const int hb = ch * 128;
        f32x4 acc1[2][4] = {};
        // ---- GEMM1: split-bf16 (hi*hi + hi*lo + lo*hi), K=64 ----
        #pragma unroll
        for (int ks = 0; ks < 2; ++ks) {
            bf16x8 ah[2], al[2];
            #pragma unroll
            for (int mf = 0; mf < 2; ++mf) {
                const int row = hb + wm * 32 + mf * 16 + c15;
                ah[mf] = *(const bf16x8*)(win_hi + row * DI + ks * 32 + g * 8);
                al[mf] = *(const bf16x8*)(win_lo + row * DI + ks * 32 + g * 8);
            }
            #pragma unroll
            for (int nf = 0; nf < 4; ++nf) {
                const int b = wn * 64 + nf * 16 + c15;
                const int off = (b * 128 + ks * 64 + g * 16) ^ ((b & 7) << 4);
                bf16x8 bh = *(const bf16x8*)((const char*)u_hi + off);
                bf16x8 bl = *(const bf16x8*)((const char*)u_lo + off);
                #pragma unroll
                for (int mf = 0; mf < 2; ++mf) {
                    acc1[mf][nf] = __builtin_amdgcn_mfma_f32_16x16x32_bf16(ah[mf], bh, acc1[mf][nf], 0, 0, 0);
                    acc1[mf][nf] = __builtin_amdgcn_mfma_f32_16x16x32_bf16(ah[mf], bl, acc1[mf][nf], 0, 0, 0);
                    acc1[mf][nf] = __builtin_amdgcn_mfma_f32_16x16x32_bf16(al[mf], bh, acc1[mf][nf], 0, 0, 0);
                }
            }
        }
        // ---- epilogue: xs = acc + base + noise; write xs; sigmoid -> s_lds (bf16) ----
        #pragma unroll
        for (int mf = 0; mf < 2; ++mf) {
            #pragma unroll
            for (int nf = 0; nf < 4; ++nf) {
                const int b = wn * 64 + nf * 16 + c15;
                const int h0 = hb + wm * 32 + mf * 16 + 4 * g;
                const size_t gi = ((size_t)t * DH + h0) * BB + b;
                const float* bp = base + (size_t)h0 * BB + b;
                const float* np = noise + gi;
                float* xp = xs + gi;
                unsigned long long ps = 0ull;
                #pragma unroll
                for (int r = 0; r < 4; ++r) {
                    float x = acc1[mf][nf][r] + bp[r * BB] + np[r * BB];
                    xp[r * BB] = x;
                    ps |= (unsigned long long)f2bf(sigm(x)) << (16 * r);
                }
                // c(h_local) = wm*32 + 8g + 4mf + r  -> 4 contiguous bf16 = 8 B
                const int off = (b * 256 + wm * 64 + g * 16 + mf * 8) ^ ((b & 7) << 4);
                *(unsigned long long*)((char*)s_lds + off) = ps;
            }
        }
        __syncthreads();
        // ---- GEMM2: acc2 += wout[:, chunk] @ s   (K=128 per chunk) ----
        const int brow = wid * 16 + c15;
        #pragma unroll
        for (int ks = 0; ks < 4; ++ks) {
            const int off = (brow * 256 + ks * 64 + g * 16) ^ ((brow & 7) << 4);
            bf16x8 bfr = *(const bf16x8*)((const char*)s_lds + off);
            #pragma unroll
            for (int mf = 0; mf < 4; ++mf) {
                const int o = mf * 16 + c15;
                bf16x8 a2 = *(const bf16x8*)(wout_p + o * DH + ch * 128 + ks * 32 + g * 8);
                acc2[mf] = __builtin_amdgcn_mfma_f32_16x16x32_bf16(a2, bfr, acc2[mf], 0, 0, 0);
            }
        }
        __syncthreads();
    }
    // ---- write outputs (T, DO, BB) ----
    const int b = wid * 16 + c15;
    #pragma unroll
    for (int mf = 0; mf < 4; ++mf) {
        const int o0 = mf * 16 + 4 * g;
        float* op = out + (size_t)t * DO_ * BB + (size_t)o0 * BB + b;
        #pragma unroll
        for (int r = 0; r < 4; ++r)
            op[r * BB] = acc2[mf][r] + bias[o0 + r];
    }
}

extern "C" void kernel_launch(void* const* d_in, const int* in_sizes, int n_in,
                              void* d_out, int out_size, void* d_ws, size_t ws_size,
                              hipStream_t stream)
{
    const float* u     = (const float*)d_in[0];   // (T, DI, B)
    const float* r0    = (const float*)d_in[1];   // (DH, B)
    const float* noise = (const float*)d_in[2];   // (T, DH, B)
    const float* win   = (const float*)d_in[3];   // (DH, DI)
    const float* w_    = (const float*)d_in[4];   // (DH, DH)
    // d_in[5] m_diag: unused — |_w * (+-1)| == |_w|
    const float* wout  = (const float*)d_in[6];   // (DO, DH)
    const float* bias  = (const float*)d_in[7];   // (DO, 1)
    const float* taus  = (const float*)d_in[8];   // (DH, 1)

    float* out = (float*)d_out;                   // outputs (T,DO,B) then xs (T,DH,B)
    float* xs  = out + (size_t)T_ * DO_ * BB;

    char* ws = (char*)d_ws;
    float* sig_r0          = (float*)(ws);                          // 1 MB
    float* base            = (float*)(ws + (1u << 20));             // 1 MB
    unsigned short* win_hi = (unsigned short*)(ws + (2u << 20));                 // 256 KB
    unsigned short* win_lo = (unsigned short*)(ws + (2u << 20) + (256u << 10)); // 256 KB
    unsigned short* wout_p = (unsigned short*)(ws + (2u << 20) + (512u << 10)); // 256 KB

    hipLaunchKernelGGL(k_prep, dim3(1024), dim3(256), 0, stream,
                       r0, win, wout, sig_r0, win_hi, win_lo, wout_p);
    hipLaunchKernelGGL(k_base, dim3(256), dim3(256), 0, stream,
                       w_, r0, taus, sig_r0, base);
    hipLaunchKernelGGL(k_main, dim3(T_), dim3(512), 0, stream,
                       u, noise, base, win_hi, win_lo, wout_p, bias, out, xs);
}